// Round 14
// baseline (182.785 us; speedup 1.0000x reference)
//
#include <hip/hip_runtime.h>
#include <hip/hip_bf16.h>

typedef __attribute__((ext_vector_type(8))) short bf16x8;
typedef __attribute__((ext_vector_type(4))) float f32x4;

__device__ inline unsigned short f2bf(float f) {          // RNE, matches __float2bfloat16
    unsigned u = __float_as_uint(f);
    unsigned r = u + 0x7fffu + ((u >> 16) & 1u);
    return (unsigned short)(r >> 16);
}
__device__ inline float bf2f(unsigned short s) {
    return __uint_as_float((unsigned)s << 16);
}

// ---------------- JAX threefry2x32 (partitionable) + normal(key=42) --------

__device__ inline unsigned rotl32(unsigned x, unsigned r) {
    return (x << r) | (x >> (32 - r));
}

__device__ inline void threefry2x32_042(unsigned c0, unsigned c1,
                                        unsigned& o0, unsigned& o1) {
    const unsigned k0 = 0u, k1 = 42u;
    unsigned ks[3] = { k0, k1, k0 ^ k1 ^ 0x1BD11BDAu };
    unsigned x0 = c0 + ks[0];
    unsigned x1 = c1 + ks[1];
    const unsigned rotA[4] = {13u, 15u, 26u, 6u};
    const unsigned rotB[4] = {17u, 29u, 16u, 24u};

    #pragma unroll
    for (int i = 0; i < 5; ++i) {
        #pragma unroll
        for (int j = 0; j < 4; ++j) {
            unsigned r = (i & 1) ? rotB[j] : rotA[j];
            x0 += x1;
            x1 = rotl32(x1, r);
            x1 ^= x0;
        }
        x0 += ks[(i + 1) % 3];
        x1 += ks[(i + 2) % 3] + (unsigned)(i + 1);
    }
    o0 = x0; o1 = x1;
}

__device__ inline float erfinv_f32(float x) {
    float w = -log1pf(-x * x);
    float p;
    if (w < 5.0f) {
        w -= 2.5f;
        p = 2.81022636e-08f;
        p = fmaf(p, w, 3.43273939e-07f);
        p = fmaf(p, w, -3.5233877e-06f);
        p = fmaf(p, w, -4.39150654e-06f);
        p = fmaf(p, w, 0.00021858087f);
        p = fmaf(p, w, -0.00125372503f);
        p = fmaf(p, w, -0.00417768164f);
        p = fmaf(p, w, 0.246640727f);
        p = fmaf(p, w, 1.50140941f);
    } else {
        w = sqrtf(w) - 3.0f;
        p = -0.000200214257f;
        p = fmaf(p, w, 0.000100950558f);
        p = fmaf(p, w, 0.00134934322f);
        p = fmaf(p, w, -0.00367342844f);
        p = fmaf(p, w, 0.00573950773f);
        p = fmaf(p, w, -0.0076224613f);
        p = fmaf(p, w, 0.00943887047f);
        p = fmaf(p, w, 1.00167406f);
        p = fmaf(p, w, 2.83297682f);
    }
    return p * x;
}

__device__ inline float jax_normal_4232(unsigned idx) {
    unsigned o0, o1;
    threefry2x32_042(0u, idx, o0, o1);
    unsigned bits = o0 ^ o1;
    unsigned fb = (bits >> 9) | 0x3f800000u;
    float f = __uint_as_float(fb) - 1.0f;              // [0, 1)
    const float lo = -0.99999994f;                     // nextafter(-1, 0)
    float u = f * (1.0f - lo) + lo;
    u = fmaxf(u, lo);
    return 1.41421356f * erfinv_f32(u);
}

// ---------------- int64/int32 index handling -------------------------------

__device__ inline int idx_at(const void* p, long long i, int is64) {
    return is64 ? (int)((const long long*)p)[i] : ((const int*)p)[i];
}

#define NBK 256
#define CAP 4864   // per-bucket edge capacity: mean 3906 + ~15 sigma

// detect dtype; also init bcnt=0 and gcur[t]=t*CAP (fixed bucket bases)
__global__ __launch_bounds__(256) void detect_idx64(const unsigned* __restrict__ raw,
                                                    int ne, int* flag,
                                                    int* __restrict__ bcnt,
                                                    int* __restrict__ gcur) {
    __shared__ int nz;
    if (threadIdx.x == 0) nz = 0;
    bcnt[threadIdx.x] = 0;
    gcur[threadIdx.x] = threadIdx.x * CAP;
    __syncthreads();
    int stride = ne / 2048;
    if (stride < 1) stride = 1;
    for (int k = threadIdx.x; k < 2048; k += 256) {
        long long j = (long long)k * stride;
        if (j < ne && raw[2 * j + 1] != 0u) nz = 1;
    }
    __syncthreads();
    if (threadIdx.x == 0) flag[0] = (nz == 0) ? 1 : 0;
}

// ---------------- single-pass bucketed edge partition ----------------------
// pairs entry: (dloc << 17) | src   (dloc < 512, src < 2^17)

#define CHUNK_MAX 4096

__global__ __launch_bounds__(256) void bucket_fill(const void* __restrict__ ei,
                                                   const int* __restrict__ flag,
                                                   int* __restrict__ gcur,
                                                   int* __restrict__ bcnt,
                                                   int* __restrict__ pairs,
                                                   int ne, int npb, int chunk) {
    __shared__ int hist[NBK];
    __shared__ int basecur[NBK];
    __shared__ int pbuf[CHUNK_MAX];
    __shared__ unsigned char bbuf[CHUNK_MAX];
    int t = threadIdx.x;
    hist[t] = 0;
    __syncthreads();
    int is64 = flag[0];
    int c0 = blockIdx.x * chunk;
    int c1 = c0 + chunk; if (c1 > ne) c1 = ne;
    for (int i = c0 + t; i < c1; i += 256) {
        int s = idx_at(ei, i, is64);
        int d = idx_at(ei, (long long)ne + i, is64);
        int bb = d / npb;
        int dloc = d - bb * npb;
        pbuf[i - c0] = (dloc << 17) | s;
        bbuf[i - c0] = (unsigned char)bb;
        atomicAdd(&hist[bb], 1);
    }
    __syncthreads();
    if (hist[t] > 0) {
        basecur[t] = atomicAdd(&gcur[t], hist[t]);
        atomicAdd(&bcnt[t], hist[t]);
    }
    __syncthreads();
    int nloc = c1 - c0;
    for (int li = t; li < nloc; li += 256) {
        int bb = bbuf[li];
        int slot = atomicAdd(&basecur[bb], 1);
        if (slot < (bb + 1) * CAP) pairs[slot] = pbuf[li];
    }
}

// one block per bucket: LDS degree histogram -> wave scan -> rowptr/deg/dinv,
// LDS-cursor fill of csr_src; also zeroes sums (gtot floats, 256 blocks)
#define NPB_MAX 512
__global__ __launch_bounds__(256) void csr_build(const int* __restrict__ pairs,
                                                 const int* __restrict__ bcnt,
                                                 int* __restrict__ rowptr,
                                                 int* __restrict__ degarr,
                                                 float* __restrict__ dinv,
                                                 int* __restrict__ csr_src,
                                                 float* __restrict__ sums, int gtot,
                                                 int n, int npb) {
    __shared__ int cnt[NPB_MAX];
    __shared__ int cur[NPB_MAX];
    int b = blockIdx.x;
    int t = threadIdx.x;
    int gi = b * 256 + t;
    if (gi < gtot) sums[gi] = 0.0f;
    int bstart = b * npb;
    int bn = n - bstart; if (bn > npb) bn = npb;
    if (bn <= 0) return;
    int e0 = b * CAP;
    int count = bcnt[b]; if (count > CAP) count = CAP;
    int e1 = e0 + count;

    for (int i = t; i < bn; i += 256) cnt[i] = 0;
    __syncthreads();
    for (int i = e0 + t; i < e1; i += 256)
        atomicAdd(&cnt[pairs[i] >> 17], 1);
    __syncthreads();

    if (t < 64) {
        int running = 0;
        for (int base2 = 0; base2 < bn; base2 += 64) {
            int idx2 = base2 + t;
            int v = (idx2 < bn) ? cnt[idx2] : 0;
            int orig = v;
            #pragma unroll
            for (int off = 1; off < 64; off <<= 1) {
                int tmp = __shfl_up(v, off);
                if (t >= off) v += tmp;
            }
            if (idx2 < bn) cur[idx2] = e0 + running + (v - orig);
            running += __shfl(v, 63);
        }
    }
    __syncthreads();

    for (int ln = t; ln < bn; ln += 256) {
        rowptr[bstart + ln] = cur[ln];
        degarr[bstart + ln] = cnt[ln];
        dinv[bstart + ln] = rsqrtf((float)cnt[ln] + 1.0f);
    }
    __syncthreads();

    for (int i = e0 + t; i < e1; i += 256) {
        int p = pairs[i];
        int slot = atomicAdd(&cur[p >> 17], 1);
        csr_src[slot] = p & 0x1FFFF;
    }
}

// ---------------- MFMA 64x64 linear layers ---------------------------------
// Output layout is SLICED: Y[cb][row][16], cb=0..3 (16-column chunks), so the
// gather's per-slice table (N x 16 bf16 = 3.2 MB) is L2-resident.

__device__ inline void load_wfrags(const float* __restrict__ W,
                                   int cq, int cr, bf16x8 wf[2][4]) {
    #pragma unroll
    for (int ks = 0; ks < 2; ++ks)
        #pragma unroll
        for (int cb = 0; cb < 4; ++cb) {
            bf16x8 v;
            #pragma unroll
            for (int j = 0; j < 8; ++j) {
                int k = ks * 32 + cq * 8 + j;
                v[j] = (short)f2bf(W[k * 64 + cb * 16 + cr]);
            }
            wf[ks][cb] = v;
        }
}

__device__ inline void mfma_store(f32x4 acc[4], const float* __restrict__ dinv,
                                  unsigned short* __restrict__ Y,
                                  int rowbase, int cq, int cr, int nrows,
                                  size_t n16) {
    #pragma unroll
    for (int reg = 0; reg < 4; ++reg) {
        int r = rowbase + cq * 4 + reg;
        if (r < nrows) {
            float dv = dinv[r];
            #pragma unroll
            for (int cb = 0; cb < 4; ++cb)
                Y[(size_t)cb * n16 + (size_t)r * 16 + cr] = f2bf(acc[cb][reg] * dv);
        }
    }
}

__global__ __launch_bounds__(256) void lin64_mfma_f32(const float* __restrict__ X,
                                                      const float* __restrict__ W,
                                                      const float* __restrict__ dinv,
                                                      unsigned short* __restrict__ Y,
                                                      int nrows) {
    int t = threadIdx.x;
    int lane = t & 63, wid = t >> 6;
    int cq = lane >> 4, cr = lane & 15;
    size_t n16 = (size_t)nrows * 16;
    bf16x8 wf[2][4];
    load_wfrags(W, cq, cr, wf);
    int rowbase = (blockIdx.x * 4 + wid) * 16;
    if (rowbase >= nrows) return;
    int arow = rowbase + cr; if (arow >= nrows) arow = nrows - 1;
    const float* xr = X + (size_t)arow * 64;
    bf16x8 af[2];
    #pragma unroll
    for (int ks = 0; ks < 2; ++ks) {
        const float4* p = (const float4*)(xr + ks * 32 + cq * 8);
        float4 a = p[0], b = p[1];
        bf16x8 v;
        v[0] = (short)f2bf(a.x); v[1] = (short)f2bf(a.y);
        v[2] = (short)f2bf(a.z); v[3] = (short)f2bf(a.w);
        v[4] = (short)f2bf(b.x); v[5] = (short)f2bf(b.y);
        v[6] = (short)f2bf(b.z); v[7] = (short)f2bf(b.w);
        af[ks] = v;
    }
    f32x4 z = {0.0f, 0.0f, 0.0f, 0.0f};
    f32x4 acc[4] = {z, z, z, z};
    #pragma unroll
    for (int ks = 0; ks < 2; ++ks)
        #pragma unroll
        for (int cb = 0; cb < 4; ++cb)
            acc[cb] = __builtin_amdgcn_mfma_f32_16x16x32_bf16(af[ks], wf[ks][cb],
                                                              acc[cb], 0, 0, 0);
    mfma_store(acc, dinv, Y, rowbase, cq, cr, nrows, n16);
}

// conv2: X bf16 SLICED, fused relu(X + bin); Y sliced
__global__ __launch_bounds__(256) void lin64_mfma_bf16(const unsigned short* __restrict__ X,
                                                       const float* __restrict__ bin,
                                                       const float* __restrict__ W,
                                                       const float* __restrict__ dinv,
                                                       unsigned short* __restrict__ Y,
                                                       int nrows) {
    int t = threadIdx.x;
    int lane = t & 63, wid = t >> 6;
    int cq = lane >> 4, cr = lane & 15;
    size_t n16 = (size_t)nrows * 16;
    bf16x8 wf[2][4];
    load_wfrags(W, cq, cr, wf);
    float bpre[2][8];
    #pragma unroll
    for (int ks = 0; ks < 2; ++ks)
        #pragma unroll
        for (int j = 0; j < 8; ++j)
            bpre[ks][j] = bin[ks * 32 + cq * 8 + j];
    int rowbase = (blockIdx.x * 4 + wid) * 16;
    if (rowbase >= nrows) return;
    int arow = rowbase + cr; if (arow >= nrows) arow = nrows - 1;
    bf16x8 af[2];
    #pragma unroll
    for (int ks = 0; ks < 2; ++ks) {
        int cbk = ks * 2 + (cq >> 1);                     // 16-col chunk index
        const bf16x8 raw = *(const bf16x8*)(X + (size_t)cbk * n16 +
                                            (size_t)arow * 16 + (cq & 1) * 8);
        bf16x8 v;
        #pragma unroll
        for (int j = 0; j < 8; ++j) {
            float vv = bf2f((unsigned short)raw[j]) + bpre[ks][j];
            v[j] = (short)f2bf(fmaxf(vv, 0.0f));
        }
        af[ks] = v;
    }
    f32x4 z = {0.0f, 0.0f, 0.0f, 0.0f};
    f32x4 acc[4] = {z, z, z, z};
    #pragma unroll
    for (int ks = 0; ks < 2; ++ks)
        #pragma unroll
        for (int cb = 0; cb < 4; ++cb)
            acc[cb] = __builtin_amdgcn_mfma_f32_16x16x32_bf16(af[ks], wf[ks][cb],
                                                              acc[cb], 0, 0, 0);
    mfma_store(acc, dinv, Y, rowbase, cq, cr, nrows, n16);
}

// ---------------- gather / pool / head -------------------------------------

__device__ inline float tree16(const float v[16]) {
    float s0 = (v[0] + v[1]) + (v[2] + v[3]);
    float s1 = (v[4] + v[5]) + (v[6] + v[7]);
    float s2 = (v[8] + v[9]) + (v[10] + v[11]);
    float s3 = (v[12] + v[13]) + (v[14] + v[15]);
    return (s0 + s1) + (s2 + s3);
}

// Column-sliced gather: grid.y = slice (16 cols, table 3.2MB -> L2-resident).
// Each wave: 4 nodes x 16 lanes. Masked batch-16 rounds, shfl width 16.
__global__ __launch_bounds__(256) void gcn_gather_sl(const unsigned short* __restrict__ A,
                                                     const float* __restrict__ dinv,
                                                     const int* __restrict__ rowptr,
                                                     const int* __restrict__ degarr,
                                                     const int* __restrict__ csr_src,
                                                     unsigned short* __restrict__ B, int n) {
    int t = threadIdx.x;
    size_t n16 = (size_t)n * 16;
    const unsigned short* As = A + (size_t)blockIdx.y * n16;
    unsigned short* Bs = B + (size_t)blockIdx.y * n16;
    int wid = t >> 6;
    int sub = (t >> 4) & 3;
    int cl = t & 15;
    int node = (blockIdx.x * 4 + wid) * 4 + sub;
    int vnode = node < n ? node : n - 1;
    float acc = bf2f(As[(size_t)vnode * 16 + cl]);        // self loop
    int beg = rowptr[vnode];
    int m = (node < n) ? degarr[vnode] : 0;               // group-uniform
    int mA = __shfl(m, 0), mB = __shfl(m, 16);
    int mC = __shfl(m, 32), mD = __shfl(m, 48);
    int mw = max(max(mA, mB), max(mC, mD));               // wave-uniform
    for (int j0 = 0; j0 < mw; j0 += 16) {
        int e = j0 + cl;
        int eidx = beg + (e < m ? e : (m > 0 ? m - 1 : 0));
        int sl = csr_src[eidx];
        int mm = m - j0;                                  // group-uniform
        int sidx[16];
        #pragma unroll
        for (int j = 0; j < 16; ++j) sidx[j] = __shfl(sl, j, 16);
        float v[16];
        #pragma unroll
        for (int j = 0; j < 16; ++j) v[j] = bf2f(As[(size_t)sidx[j] * 16 + cl]);
        #pragma unroll
        for (int j = 0; j < 16; ++j) v[j] = (j < mm) ? v[j] : 0.0f;
        acc += tree16(v);
    }
    if (node < n) Bs[(size_t)node * 16 + cl] = f2bf(acc * dinv[node]);
}

// Segmented pooling over sorted batch; X is SLICED bf16.
#define POOL_NPW 16
__global__ __launch_bounds__(256) void pool_seg(const __hip_bfloat16* __restrict__ X,
                                                const float* __restrict__ b,
                                                const void* __restrict__ batch,
                                                const int* __restrict__ flag,
                                                float* __restrict__ sums,
                                                float* __restrict__ counts, int n) {
    int t = threadIdx.x;
    int c = t & 63;
    int wid = blockIdx.x * 4 + (t >> 6);
    int s0 = wid * POOL_NPW;
    if (s0 >= n) return;
    int s1 = s0 + POOL_NPW; if (s1 > n) s1 = n;
    int is64 = flag[0];
    size_t n16 = (size_t)n * 16;
    const __hip_bfloat16* Xc = X + (size_t)(c >> 4) * n16 + (c & 15);
    float bc = b[c];
    float acc = 0.0f, cnt = 0.0f;
    int cur = idx_at(batch, s0, is64);
    int i = s0;
    for (; i + 4 <= s1; i += 4) {
        int g0 = idx_at(batch, i + 0, is64);
        int g1 = idx_at(batch, i + 1, is64);
        int g2 = idx_at(batch, i + 2, is64);
        int g3 = idx_at(batch, i + 3, is64);
        float v0 = __bfloat162float(Xc[(size_t)(i + 0) * 16]);
        float v1 = __bfloat162float(Xc[(size_t)(i + 1) * 16]);
        float v2 = __bfloat162float(Xc[(size_t)(i + 2) * 16]);
        float v3 = __bfloat162float(Xc[(size_t)(i + 3) * 16]);
        if (g0 != cur) {
            atomicAdd(&sums[(size_t)cur * 64 + c], acc);
            if (c == 0) atomicAdd(&counts[cur], cnt);
            acc = 0.0f; cnt = 0.0f; cur = g0;
        }
        acc += fmaxf(v0 + bc, 0.0f); cnt += 1.0f;
        if (g1 != cur) {
            atomicAdd(&sums[(size_t)cur * 64 + c], acc);
            if (c == 0) atomicAdd(&counts[cur], cnt);
            acc = 0.0f; cnt = 0.0f; cur = g1;
        }
        acc += fmaxf(v1 + bc, 0.0f); cnt += 1.0f;
        if (g2 != cur) {
            atomicAdd(&sums[(size_t)cur * 64 + c], acc);
            if (c == 0) atomicAdd(&counts[cur], cnt);
            acc = 0.0f; cnt = 0.0f; cur = g2;
        }
        acc += fmaxf(v2 + bc, 0.0f); cnt += 1.0f;
        if (g3 != cur) {
            atomicAdd(&sums[(size_t)cur * 64 + c], acc);
            if (c == 0) atomicAdd(&counts[cur], cnt);
            acc = 0.0f; cnt = 0.0f; cur = g3;
        }
        acc += fmaxf(v3 + bc, 0.0f); cnt += 1.0f;
    }
    for (; i < s1; ++i) {
        int g0 = idx_at(batch, i, is64);
        float v0 = __bfloat162float(Xc[(size_t)i * 16]);
        if (g0 != cur) {
            atomicAdd(&sums[(size_t)cur * 64 + c], acc);
            if (c == 0) atomicAdd(&counts[cur], cnt);
            acc = 0.0f; cnt = 0.0f; cur = g0;
        }
        acc += fmaxf(v0 + bc, 0.0f); cnt += 1.0f;
    }
    atomicAdd(&sums[(size_t)cur * 64 + c], acc);
    if (c == 0) atomicAdd(&counts[cur], cnt);
}

__global__ __launch_bounds__(64) void vae_head(const float* __restrict__ sums,
                                               const float* __restrict__ counts,
                                               const float* __restrict__ Wmu,
                                               const float* __restrict__ bmu,
                                               const float* __restrict__ Wlv,
                                               const float* __restrict__ blv,
                                               const float* __restrict__ Wd1,
                                               const float* __restrict__ bd1,
                                               const float* __restrict__ Wd2,
                                               const float* __restrict__ bd2,
                                               float* __restrict__ out) {
    int g = blockIdx.x;
    int t = threadIdx.x;  // 64 threads
    __shared__ float sp[64];
    __shared__ float sz[32];
    __shared__ float sh[64];

    float cnt = fmaxf(counts[g], 1.0f);
    sp[t] = sums[(size_t)g * 64 + t] / cnt;
    __syncthreads();

    if (t < 32) {
        float mu = bmu[t];
        float lv = blv[t];
        #pragma unroll
        for (int k = 0; k < 64; ++k) {
            float pk = sp[k];
            mu = fmaf(pk, Wmu[k * 32 + t], mu);
            lv = fmaf(pk, Wlv[k * 32 + t], lv);
        }
        unsigned idx = (unsigned)(g * 32 + t);
        float eps = jax_normal_4232(idx);
        float z = fmaf(eps, expf(0.5f * lv), mu);
        sz[t] = z;
        out[16384 + (size_t)g * 32 + t] = mu;       // mu block
        out[24576 + (size_t)g * 32 + t] = lv;       // logvar block
    }
    __syncthreads();

    float h = bd1[t];
    #pragma unroll
    for (int k = 0; k < 32; ++k) h = fmaf(sz[k], Wd1[k * 64 + t], h);
    h = fmaxf(h, 0.0f);
    sh[t] = h;
    __syncthreads();

    float r = bd2[t];
    #pragma unroll
    for (int k = 0; k < 64; ++k) r = fmaf(sh[k], Wd2[k * 64 + t], r);
    out[(size_t)g * 64 + t] = r;                    // recon block
}

// ---------------- launch ----------------------------------------------------

extern "C" void kernel_launch(void* const* d_in, const int* in_sizes, int n_in,
                              void* d_out, int out_size, void* d_ws, size_t ws_size,
                              hipStream_t stream) {
    const float* x    = (const float*)d_in[0];
    const void*  ei   = d_in[1];
    const void*  batch= d_in[2];
    const float* W1   = (const float*)d_in[3];
    const float* b1   = (const float*)d_in[4];
    const float* W2   = (const float*)d_in[5];
    const float* b2   = (const float*)d_in[6];
    const float* Wmu  = (const float*)d_in[7];
    const float* bmu  = (const float*)d_in[8];
    const float* Wlv  = (const float*)d_in[9];
    const float* blv  = (const float*)d_in[10];
    const float* Wd1  = (const float*)d_in[11];
    const float* bd1  = (const float*)d_in[12];
    const float* Wd2  = (const float*)d_in[13];
    const float* bd2  = (const float*)d_in[14];

    const int N = in_sizes[0] / 64;       // 100000
    const int E = in_sizes[1] / 2;        // 1000000
    const int G = 256;

    const int NPB = (N + NBK - 1) / NBK;          // 391 nodes per bucket
    const int nbu = (N + NPB - 1) / NPB;          // 256 buckets

    float* out = (float*)d_out;

    // workspace layout
    float* dinv = (float*)d_ws;                          // Npad floats
    __hip_bfloat16* A = (__hip_bfloat16*)(dinv + ((N + 255) & ~255)); // 4 slices x N x 16
    __hip_bfloat16* B = A + (size_t)N * 64;              // 4 slices x N x 16
    float* sums = (float*)(B + (size_t)N * 64);          // G*64
    float* cnts = sums + (size_t)G * 64;                 // G
    int*   flag = (int*)(cnts + G);                      // 1 (+pad to 256)
    int*   rowptr = flag + 256;                          // N (+pad)
    int*   degarr = rowptr + ((N + 255) & ~255);         // N (+pad)
    int*   bcnt = degarr + ((N + 255) & ~255);           // 256
    int*   gcur = bcnt + 256;                            // 256
    int*   csr_src = gcur + 256;                         // nbu*CAP
    int*   pairs = csr_src + (size_t)nbu * CAP;          // nbu*CAP (packed)

    const int blkLin   = (N + 63) / 64;                  // 16 rows/wave, 4 waves/blk
    const int blkPool  = (N + POOL_NPW * 4 - 1) / (POOL_NPW * 4);
    const int chunkE   = (E + NBK - 1) / NBK;            // edges per fill block (<=4096)
    const int gtot     = G * 64 + G;
    dim3 gridG((N + 15) / 16, 4);                        // x: node groups, y: slice

    // index dtype detection + bcnt/gcur init
    detect_idx64<<<1, 256, 0, stream>>>((const unsigned*)ei, E, flag, bcnt, gcur);

    // single-pass bucketed partition + CSR build (csr_build also zeroes sums)
    bucket_fill<<<NBK, 256, 0, stream>>>(ei, flag, gcur, bcnt, pairs, E, NPB, chunkE);
    csr_build<<<nbu, 256, 0, stream>>>(pairs, bcnt, rowptr, degarr, dinv, csr_src,
                                       sums, gtot, N, NPB);

    // conv1: A = bf16(x@W1 * dinv) sliced ; B = bf16(gather(A) * dinv) sliced
    lin64_mfma_f32<<<blkLin, 256, 0, stream>>>(x, W1, dinv, (unsigned short*)A, N);
    gcn_gather_sl<<<gridG, 256, 0, stream>>>((const unsigned short*)A, dinv,
                                             rowptr, degarr, csr_src,
                                             (unsigned short*)B, N);

    // conv2: A = bf16(relu(B+b1)@W2 * dinv) sliced ; B = bf16(gather(A) * dinv)
    lin64_mfma_bf16<<<blkLin, 256, 0, stream>>>((const unsigned short*)B, b1, W2,
                                                dinv, (unsigned short*)A, N);
    gcn_gather_sl<<<gridG, 256, 0, stream>>>((const unsigned short*)A, dinv,
                                             rowptr, degarr, csr_src,
                                             (unsigned short*)B, N);

    // pool (applies relu(B+b2)) + head
    pool_seg<<<blkPool, 256, 0, stream>>>(B, b2, batch, flag, sums, cnts, N);
    vae_head<<<G, 64, 0, stream>>>(sums, cnts, Wmu, bmu, Wlv, blv,
                                   Wd1, bd1, Wd2, bd2, out);
}

// Round 15
// 170.531 us; speedup vs baseline: 1.0719x; 1.0719x over previous
//
#include <hip/hip_runtime.h>
#include <hip/hip_bf16.h>

typedef __attribute__((ext_vector_type(8))) short bf16x8;
typedef __attribute__((ext_vector_type(4))) float f32x4;

__device__ inline unsigned short f2bf(float f) {          // RNE, matches __float2bfloat16
    unsigned u = __float_as_uint(f);
    unsigned r = u + 0x7fffu + ((u >> 16) & 1u);
    return (unsigned short)(r >> 16);
}
__device__ inline float bf2f(unsigned short s) {
    return __uint_as_float((unsigned)s << 16);
}

// ---------------- JAX threefry2x32 (partitionable) + normal(key=42) --------

__device__ inline unsigned rotl32(unsigned x, unsigned r) {
    return (x << r) | (x >> (32 - r));
}

__device__ inline void threefry2x32_042(unsigned c0, unsigned c1,
                                        unsigned& o0, unsigned& o1) {
    const unsigned k0 = 0u, k1 = 42u;
    unsigned ks[3] = { k0, k1, k0 ^ k1 ^ 0x1BD11BDAu };
    unsigned x0 = c0 + ks[0];
    unsigned x1 = c1 + ks[1];
    const unsigned rotA[4] = {13u, 15u, 26u, 6u};
    const unsigned rotB[4] = {17u, 29u, 16u, 24u};

    #pragma unroll
    for (int i = 0; i < 5; ++i) {
        #pragma unroll
        for (int j = 0; j < 4; ++j) {
            unsigned r = (i & 1) ? rotB[j] : rotA[j];
            x0 += x1;
            x1 = rotl32(x1, r);
            x1 ^= x0;
        }
        x0 += ks[(i + 1) % 3];
        x1 += ks[(i + 2) % 3] + (unsigned)(i + 1);
    }
    o0 = x0; o1 = x1;
}

__device__ inline float erfinv_f32(float x) {
    float w = -log1pf(-x * x);
    float p;
    if (w < 5.0f) {
        w -= 2.5f;
        p = 2.81022636e-08f;
        p = fmaf(p, w, 3.43273939e-07f);
        p = fmaf(p, w, -3.5233877e-06f);
        p = fmaf(p, w, -4.39150654e-06f);
        p = fmaf(p, w, 0.00021858087f);
        p = fmaf(p, w, -0.00125372503f);
        p = fmaf(p, w, -0.00417768164f);
        p = fmaf(p, w, 0.246640727f);
        p = fmaf(p, w, 1.50140941f);
    } else {
        w = sqrtf(w) - 3.0f;
        p = -0.000200214257f;
        p = fmaf(p, w, 0.000100950558f);
        p = fmaf(p, w, 0.00134934322f);
        p = fmaf(p, w, -0.00367342844f);
        p = fmaf(p, w, 0.00573950773f);
        p = fmaf(p, w, -0.0076224613f);
        p = fmaf(p, w, 0.00943887047f);
        p = fmaf(p, w, 1.00167406f);
        p = fmaf(p, w, 2.83297682f);
    }
    return p * x;
}

__device__ inline float jax_normal_4232(unsigned idx) {
    unsigned o0, o1;
    threefry2x32_042(0u, idx, o0, o1);
    unsigned bits = o0 ^ o1;
    unsigned fb = (bits >> 9) | 0x3f800000u;
    float f = __uint_as_float(fb) - 1.0f;              // [0, 1)
    const float lo = -0.99999994f;                     // nextafter(-1, 0)
    float u = f * (1.0f - lo) + lo;
    u = fmaxf(u, lo);
    return 1.41421356f * erfinv_f32(u);
}

// ---------------- int64/int32 index handling -------------------------------

__device__ inline int idx_at(const void* p, long long i, int is64) {
    return is64 ? (int)((const long long*)p)[i] : ((const int*)p)[i];
}

#define NBK 256
#define CAP 4864   // per-bucket edge capacity: mean 3906 + ~15 sigma

// detect dtype; also init bcnt=0 and gcur[t]=t*CAP (fixed bucket bases)
__global__ __launch_bounds__(256) void detect_idx64(const unsigned* __restrict__ raw,
                                                    int ne, int* flag,
                                                    int* __restrict__ bcnt,
                                                    int* __restrict__ gcur) {
    __shared__ int nz;
    if (threadIdx.x == 0) nz = 0;
    bcnt[threadIdx.x] = 0;
    gcur[threadIdx.x] = threadIdx.x * CAP;
    __syncthreads();
    int stride = ne / 2048;
    if (stride < 1) stride = 1;
    for (int k = threadIdx.x; k < 2048; k += 256) {
        long long j = (long long)k * stride;
        if (j < ne && raw[2 * j + 1] != 0u) nz = 1;
    }
    __syncthreads();
    if (threadIdx.x == 0) flag[0] = (nz == 0) ? 1 : 0;
}

// ---------------- single-pass bucketed edge partition ----------------------

#define CHUNK_MAX 4096

__global__ __launch_bounds__(256) void bucket_fill(const void* __restrict__ ei,
                                                   const int* __restrict__ flag,
                                                   int* __restrict__ gcur,
                                                   int* __restrict__ bcnt,
                                                   int2* __restrict__ pairs,
                                                   int ne, int npb, int chunk) {
    __shared__ int hist[NBK];
    __shared__ int basecur[NBK];
    __shared__ int sbuf[CHUNK_MAX];
    __shared__ int dbuf[CHUNK_MAX];
    int t = threadIdx.x;
    hist[t] = 0;
    __syncthreads();
    int is64 = flag[0];
    int c0 = blockIdx.x * chunk;
    int c1 = c0 + chunk; if (c1 > ne) c1 = ne;
    for (int i = c0 + t; i < c1; i += 256) {
        int s = idx_at(ei, i, is64);
        int d = idx_at(ei, (long long)ne + i, is64);
        sbuf[i - c0] = s;
        dbuf[i - c0] = d;
        atomicAdd(&hist[d / npb], 1);
    }
    __syncthreads();
    if (hist[t] > 0) {
        basecur[t] = atomicAdd(&gcur[t], hist[t]);
        atomicAdd(&bcnt[t], hist[t]);
    }
    __syncthreads();
    int nloc = c1 - c0;
    for (int li = t; li < nloc; li += 256) {
        int d = dbuf[li];
        int bb = d / npb;
        int slot = atomicAdd(&basecur[bb], 1);
        if (slot < (bb + 1) * CAP) pairs[slot] = make_int2(sbuf[li], d);
    }
}

// one block per bucket: LDS degree histogram -> wave scan -> rowptr/deg/dinv,
// LDS-cursor fill of csr_src; also zeroes sums (gtot floats, 256 blocks)
#define NPB_MAX 512
__global__ __launch_bounds__(256) void csr_build(const int2* __restrict__ pairs,
                                                 const int* __restrict__ bcnt,
                                                 int* __restrict__ rowptr,
                                                 int* __restrict__ degarr,
                                                 float* __restrict__ dinv,
                                                 int* __restrict__ csr_src,
                                                 float* __restrict__ sums, int gtot,
                                                 int n, int npb) {
    __shared__ int cnt[NPB_MAX];
    __shared__ int cur[NPB_MAX];
    int b = blockIdx.x;
    int t = threadIdx.x;
    int gi = b * 256 + t;
    if (gi < gtot) sums[gi] = 0.0f;
    int bstart = b * npb;
    int bn = n - bstart; if (bn > npb) bn = npb;
    if (bn <= 0) return;
    int e0 = b * CAP;
    int count = bcnt[b]; if (count > CAP) count = CAP;
    int e1 = e0 + count;

    for (int i = t; i < bn; i += 256) cnt[i] = 0;
    __syncthreads();
    for (int i = e0 + t; i < e1; i += 256)
        atomicAdd(&cnt[pairs[i].y - bstart], 1);
    __syncthreads();

    if (t < 64) {
        int running = 0;
        for (int base2 = 0; base2 < bn; base2 += 64) {
            int idx2 = base2 + t;
            int v = (idx2 < bn) ? cnt[idx2] : 0;
            int orig = v;
            #pragma unroll
            for (int off = 1; off < 64; off <<= 1) {
                int tmp = __shfl_up(v, off);
                if (t >= off) v += tmp;
            }
            if (idx2 < bn) cur[idx2] = e0 + running + (v - orig);
            running += __shfl(v, 63);
        }
    }
    __syncthreads();

    for (int ln = t; ln < bn; ln += 256) {
        rowptr[bstart + ln] = cur[ln];
        degarr[bstart + ln] = cnt[ln];
        dinv[bstart + ln] = rsqrtf((float)cnt[ln] + 1.0f);
    }
    __syncthreads();

    for (int i = e0 + t; i < e1; i += 256) {
        int2 p = pairs[i];
        int slot = atomicAdd(&cur[p.y - bstart], 1);
        csr_src[slot] = p.x;
    }
}

// ---------------- MFMA 64x64 linear layers ---------------------------------

__device__ inline void load_wfrags(const float* __restrict__ W,
                                   int cq, int cr, bf16x8 wf[2][4]) {
    #pragma unroll
    for (int ks = 0; ks < 2; ++ks)
        #pragma unroll
        for (int cb = 0; cb < 4; ++cb) {
            bf16x8 v;
            #pragma unroll
            for (int j = 0; j < 8; ++j) {
                int k = ks * 32 + cq * 8 + j;
                v[j] = (short)f2bf(W[k * 64 + cb * 16 + cr]);
            }
            wf[ks][cb] = v;
        }
}

__device__ inline void mfma_store(f32x4 acc[4], const float* __restrict__ dinv,
                                  unsigned short* __restrict__ Y,
                                  int rowbase, int cq, int cr, int nrows) {
    #pragma unroll
    for (int reg = 0; reg < 4; ++reg) {
        int r = rowbase + cq * 4 + reg;
        if (r < nrows) {
            float dv = dinv[r];
            #pragma unroll
            for (int cb = 0; cb < 4; ++cb)
                Y[(size_t)r * 64 + cb * 16 + cr] = f2bf(acc[cb][reg] * dv);
        }
    }
}

__global__ __launch_bounds__(256) void lin64_mfma_f32(const float* __restrict__ X,
                                                      const float* __restrict__ W,
                                                      const float* __restrict__ dinv,
                                                      unsigned short* __restrict__ Y,
                                                      int nrows) {
    int t = threadIdx.x;
    int lane = t & 63, wid = t >> 6;
    int cq = lane >> 4, cr = lane & 15;
    bf16x8 wf[2][4];
    load_wfrags(W, cq, cr, wf);
    int rowbase = (blockIdx.x * 4 + wid) * 16;
    if (rowbase >= nrows) return;
    int arow = rowbase + cr; if (arow >= nrows) arow = nrows - 1;
    const float* xr = X + (size_t)arow * 64;
    bf16x8 af[2];
    #pragma unroll
    for (int ks = 0; ks < 2; ++ks) {
        const float4* p = (const float4*)(xr + ks * 32 + cq * 8);
        float4 a = p[0], b = p[1];
        bf16x8 v;
        v[0] = (short)f2bf(a.x); v[1] = (short)f2bf(a.y);
        v[2] = (short)f2bf(a.z); v[3] = (short)f2bf(a.w);
        v[4] = (short)f2bf(b.x); v[5] = (short)f2bf(b.y);
        v[6] = (short)f2bf(b.z); v[7] = (short)f2bf(b.w);
        af[ks] = v;
    }
    f32x4 z = {0.0f, 0.0f, 0.0f, 0.0f};
    f32x4 acc[4] = {z, z, z, z};
    #pragma unroll
    for (int ks = 0; ks < 2; ++ks)
        #pragma unroll
        for (int cb = 0; cb < 4; ++cb)
            acc[cb] = __builtin_amdgcn_mfma_f32_16x16x32_bf16(af[ks], wf[ks][cb],
                                                              acc[cb], 0, 0, 0);
    mfma_store(acc, dinv, Y, rowbase, cq, cr, nrows);
}

__global__ __launch_bounds__(256) void lin64_mfma_bf16(const unsigned short* __restrict__ X,
                                                       const float* __restrict__ bin,
                                                       const float* __restrict__ W,
                                                       const float* __restrict__ dinv,
                                                       unsigned short* __restrict__ Y,
                                                       int nrows) {
    int t = threadIdx.x;
    int lane = t & 63, wid = t >> 6;
    int cq = lane >> 4, cr = lane & 15;
    bf16x8 wf[2][4];
    load_wfrags(W, cq, cr, wf);
    float bpre[2][8];
    #pragma unroll
    for (int ks = 0; ks < 2; ++ks)
        #pragma unroll
        for (int j = 0; j < 8; ++j)
            bpre[ks][j] = bin[ks * 32 + cq * 8 + j];
    int rowbase = (blockIdx.x * 4 + wid) * 16;
    if (rowbase >= nrows) return;
    int arow = rowbase + cr; if (arow >= nrows) arow = nrows - 1;
    const unsigned short* xr = X + (size_t)arow * 64;
    bf16x8 af[2];
    #pragma unroll
    for (int ks = 0; ks < 2; ++ks) {
        bf16x8 raw = *(const bf16x8*)(xr + ks * 32 + cq * 8);
        bf16x8 v;
        #pragma unroll
        for (int j = 0; j < 8; ++j) {
            float vv = bf2f((unsigned short)raw[j]) + bpre[ks][j];
            v[j] = (short)f2bf(fmaxf(vv, 0.0f));
        }
        af[ks] = v;
    }
    f32x4 z = {0.0f, 0.0f, 0.0f, 0.0f};
    f32x4 acc[4] = {z, z, z, z};
    #pragma unroll
    for (int ks = 0; ks < 2; ++ks)
        #pragma unroll
        for (int cb = 0; cb < 4; ++cb)
            acc[cb] = __builtin_amdgcn_mfma_f32_16x16x32_bf16(af[ks], wf[ks][cb],
                                                              acc[cb], 0, 0, 0);
    mfma_store(acc, dinv, Y, rowbase, cq, cr, nrows);
}

// ---------------- gather / pool / head -------------------------------------

__device__ inline float tree16(const float v[16]) {
    float s0 = (v[0] + v[1]) + (v[2] + v[3]);
    float s1 = (v[4] + v[5]) + (v[6] + v[7]);
    float s2 = (v[8] + v[9]) + (v[10] + v[11]);
    float s3 = (v[12] + v[13]) + (v[14] + v[15]);
    return (s0 + s1) + (s2 + s3);
}

// Full-wave column-parallel gather, masked batch-16 rounds (wave-uniform m).
// Non-temporal: csr_src read (streaming, no reuse) and B write (write-once) —
// keeps the randomly-accessed A table resident in L2.
__global__ __launch_bounds__(256) void gcn_gather(const unsigned short* __restrict__ A,
                                                  const float* __restrict__ dinv,
                                                  const int* __restrict__ rowptr,
                                                  const int* __restrict__ degarr,
                                                  const int* __restrict__ csr_src,
                                                  unsigned short* __restrict__ B, int n) {
    int t = threadIdx.x;
    int node = blockIdx.x * 4 + (t >> 6);    // wave-uniform
    int c = t & 63;
    if (node >= n) return;
    float acc = bf2f(A[(size_t)node * 64 + c]);           // self loop
    int beg = rowptr[node];
    int mt = degarr[node];
    for (int chunk = 0; chunk < mt; chunk += 64) {
        int m = mt - chunk; if (m > 64) m = 64;           // uniform
        int sl = (c < m) ? __builtin_nontemporal_load(&csr_src[beg + chunk + c]) : 0;
        for (int j0 = 0; j0 < m; j0 += 16) {
            int mm = m - j0; if (mm > 16) mm = 16;        // uniform
            int sidx[16];
            #pragma unroll
            for (int j = 0; j < 16; ++j)
                sidx[j] = __shfl(sl, j < mm ? j0 + j : j0);
            float v[16];
            #pragma unroll
            for (int j = 0; j < 16; ++j)
                v[j] = bf2f(A[(size_t)sidx[j] * 64 + c]);
            #pragma unroll
            for (int j = 0; j < 16; ++j)
                v[j] = (j < mm) ? v[j] : 0.0f;            // uniform predicate
            acc += tree16(v);
        }
    }
    __builtin_nontemporal_store(f2bf(acc * dinv[node]), &B[(size_t)node * 64 + c]);
}

#define POOL_NPW 32
__global__ __launch_bounds__(256) void pool_seg(const __hip_bfloat16* __restrict__ X,
                                                const float* __restrict__ b,
                                                const void* __restrict__ batch,
                                                const int* __restrict__ flag,
                                                float* __restrict__ sums,
                                                float* __restrict__ counts, int n) {
    int t = threadIdx.x;
    int c = t & 63;
    int wid = blockIdx.x * 4 + (t >> 6);
    int s0 = wid * POOL_NPW;
    if (s0 >= n) return;
    int s1 = s0 + POOL_NPW; if (s1 > n) s1 = n;
    int is64 = flag[0];
    float bc = b[c];
    float acc = 0.0f, cnt = 0.0f;
    int cur = idx_at(batch, s0, is64);
    int i = s0;
    for (; i + 2 <= s1; i += 2) {
        int g0 = idx_at(batch, i, is64);
        int g1 = idx_at(batch, i + 1, is64);
        float v0 = __bfloat162float(X[(size_t)i * 64 + c]);
        float v1 = __bfloat162float(X[(size_t)(i + 1) * 64 + c]);
        if (g0 != cur) {
            atomicAdd(&sums[(size_t)cur * 64 + c], acc);
            if (c == 0) atomicAdd(&counts[cur], cnt);
            acc = 0.0f; cnt = 0.0f; cur = g0;
        }
        acc += fmaxf(v0 + bc, 0.0f); cnt += 1.0f;
        if (g1 != cur) {
            atomicAdd(&sums[(size_t)cur * 64 + c], acc);
            if (c == 0) atomicAdd(&counts[cur], cnt);
            acc = 0.0f; cnt = 0.0f; cur = g1;
        }
        acc += fmaxf(v1 + bc, 0.0f); cnt += 1.0f;
    }
    if (i < s1) {
        int g0 = idx_at(batch, i, is64);
        float v0 = __bfloat162float(X[(size_t)i * 64 + c]);
        if (g0 != cur) {
            atomicAdd(&sums[(size_t)cur * 64 + c], acc);
            if (c == 0) atomicAdd(&counts[cur], cnt);
            acc = 0.0f; cnt = 0.0f; cur = g0;
        }
        acc += fmaxf(v0 + bc, 0.0f); cnt += 1.0f;
    }
    atomicAdd(&sums[(size_t)cur * 64 + c], acc);
    if (c == 0) atomicAdd(&counts[cur], cnt);
}

__global__ __launch_bounds__(64) void vae_head(const float* __restrict__ sums,
                                               const float* __restrict__ counts,
                                               const float* __restrict__ Wmu,
                                               const float* __restrict__ bmu,
                                               const float* __restrict__ Wlv,
                                               const float* __restrict__ blv,
                                               const float* __restrict__ Wd1,
                                               const float* __restrict__ bd1,
                                               const float* __restrict__ Wd2,
                                               const float* __restrict__ bd2,
                                               float* __restrict__ out) {
    int g = blockIdx.x;
    int t = threadIdx.x;  // 64 threads
    __shared__ float sp[64];
    __shared__ float sz[32];
    __shared__ float sh[64];

    float cnt = fmaxf(counts[g], 1.0f);
    sp[t] = sums[(size_t)g * 64 + t] / cnt;
    __syncthreads();

    if (t < 32) {
        float mu = bmu[t];
        float lv = blv[t];
        #pragma unroll
        for (int k = 0; k < 64; ++k) {
            float pk = sp[k];
            mu = fmaf(pk, Wmu[k * 32 + t], mu);
            lv = fmaf(pk, Wlv[k * 32 + t], lv);
        }
        unsigned idx = (unsigned)(g * 32 + t);
        float eps = jax_normal_4232(idx);
        float z = fmaf(eps, expf(0.5f * lv), mu);
        sz[t] = z;
        out[16384 + (size_t)g * 32 + t] = mu;       // mu block
        out[24576 + (size_t)g * 32 + t] = lv;       // logvar block
    }
    __syncthreads();

    float h = bd1[t];
    #pragma unroll
    for (int k = 0; k < 32; ++k) h = fmaf(sz[k], Wd1[k * 64 + t], h);
    h = fmaxf(h, 0.0f);
    sh[t] = h;
    __syncthreads();

    float r = bd2[t];
    #pragma unroll
    for (int k = 0; k < 64; ++k) r = fmaf(sh[k], Wd2[k * 64 + t], r);
    out[(size_t)g * 64 + t] = r;                    // recon block
}

// ---------------- launch ----------------------------------------------------

extern "C" void kernel_launch(void* const* d_in, const int* in_sizes, int n_in,
                              void* d_out, int out_size, void* d_ws, size_t ws_size,
                              hipStream_t stream) {
    const float* x    = (const float*)d_in[0];
    const void*  ei   = d_in[1];
    const void*  batch= d_in[2];
    const float* W1   = (const float*)d_in[3];
    const float* b1   = (const float*)d_in[4];
    const float* W2   = (const float*)d_in[5];
    const float* b2   = (const float*)d_in[6];
    const float* Wmu  = (const float*)d_in[7];
    const float* bmu  = (const float*)d_in[8];
    const float* Wlv  = (const float*)d_in[9];
    const float* blv  = (const float*)d_in[10];
    const float* Wd1  = (const float*)d_in[11];
    const float* bd1  = (const float*)d_in[12];
    const float* Wd2  = (const float*)d_in[13];
    const float* bd2  = (const float*)d_in[14];

    const int N = in_sizes[0] / 64;       // 100000
    const int E = in_sizes[1] / 2;        // 1000000
    const int G = 256;

    const int NPB = (N + NBK - 1) / NBK;          // 391 nodes per bucket
    const int nbu = (N + NPB - 1) / NPB;          // 256 buckets

    float* out = (float*)d_out;

    // workspace layout
    float* dinv = (float*)d_ws;                          // Npad floats
    __hip_bfloat16* A = (__hip_bfloat16*)(dinv + ((N + 255) & ~255)); // N*64 bf16
    __hip_bfloat16* B = A + (size_t)N * 64;              // N*64 bf16
    float* sums = (float*)(B + (size_t)N * 64);          // G*64
    float* cnts = sums + (size_t)G * 64;                 // G
    int*   flag = (int*)(cnts + G);                      // 1 (+pad to 256)
    int*   rowptr = flag + 256;                          // N (+pad)
    int*   degarr = rowptr + ((N + 255) & ~255);         // N (+pad)
    int*   bcnt = degarr + ((N + 255) & ~255);           // 256
    int*   gcur = bcnt + 256;                            // 256
    int*   csr_src = gcur + 256;                         // nbu*CAP
    int2*  pairs = (int2*)(csr_src + (((size_t)nbu * CAP + 1) & ~1ull)); // nbu*CAP

    const int blkRows  = (N + 3) / 4;
    const int blkLin   = (N + 63) / 64;                  // 16 rows/wave, 4 waves/blk
    const int blkPool  = (N + POOL_NPW * 4 - 1) / (POOL_NPW * 4);
    const int chunkE   = (E + NBK - 1) / NBK;            // edges per fill block (<=4096)
    const int gtot     = G * 64 + G;

    // index dtype detection + bcnt/gcur init
    detect_idx64<<<1, 256, 0, stream>>>((const unsigned*)ei, E, flag, bcnt, gcur);

    // single-pass bucketed partition + CSR build (csr_build also zeroes sums)
    bucket_fill<<<NBK, 256, 0, stream>>>(ei, flag, gcur, bcnt, pairs, E, NPB, chunkE);
    csr_build<<<nbu, 256, 0, stream>>>(pairs, bcnt, rowptr, degarr, dinv, csr_src,
                                       sums, gtot, N, NPB);

    // conv1: A = bf16(x@W1 * dinv) ; B = bf16(gather(A) * dinv)
    lin64_mfma_f32<<<blkLin, 256, 0, stream>>>(x, W1, dinv, (unsigned short*)A, N);
    gcn_gather<<<blkRows, 256, 0, stream>>>((const unsigned short*)A, dinv,
                                            rowptr, degarr, csr_src,
                                            (unsigned short*)B, N);

    // conv2: A = bf16(relu(B+b1)@W2 * dinv) ; B = bf16(gather(A) * dinv)
    lin64_mfma_bf16<<<blkLin, 256, 0, stream>>>((const unsigned short*)B, b1, W2,
                                                dinv, (unsigned short*)A, N);
    gcn_gather<<<blkRows, 256, 0, stream>>>((const unsigned short*)A, dinv,
                                            rowptr, degarr, csr_src,
                                            (unsigned short*)B, N);

    // pool (applies relu(B+b2)) + head
    pool_seg<<<blkPool, 256, 0, stream>>>(B, b2, batch, flag, sums, cnts, N);
    vae_head<<<G, 64, 0, stream>>>(sums, cnts, Wmu, bmu, Wlv, blv,
                                   Wd1, bd1, Wd2, bd2, out);
}

// Round 16
// 157.441 us; speedup vs baseline: 1.1610x; 1.0831x over previous
//
#include <hip/hip_runtime.h>
#include <hip/hip_bf16.h>

typedef __attribute__((ext_vector_type(8))) short bf16x8;
typedef __attribute__((ext_vector_type(4))) float f32x4;

__device__ inline unsigned short f2bf(float f) {          // RNE, matches __float2bfloat16
    unsigned u = __float_as_uint(f);
    unsigned r = u + 0x7fffu + ((u >> 16) & 1u);
    return (unsigned short)(r >> 16);
}
__device__ inline float bf2f(unsigned short s) {
    return __uint_as_float((unsigned)s << 16);
}

// ---------------- JAX threefry2x32 (partitionable) + normal(key=42) --------

__device__ inline unsigned rotl32(unsigned x, unsigned r) {
    return (x << r) | (x >> (32 - r));
}

__device__ inline void threefry2x32_042(unsigned c0, unsigned c1,
                                        unsigned& o0, unsigned& o1) {
    const unsigned k0 = 0u, k1 = 42u;
    unsigned ks[3] = { k0, k1, k0 ^ k1 ^ 0x1BD11BDAu };
    unsigned x0 = c0 + ks[0];
    unsigned x1 = c1 + ks[1];
    const unsigned rotA[4] = {13u, 15u, 26u, 6u};
    const unsigned rotB[4] = {17u, 29u, 16u, 24u};

    #pragma unroll
    for (int i = 0; i < 5; ++i) {
        #pragma unroll
        for (int j = 0; j < 4; ++j) {
            unsigned r = (i & 1) ? rotB[j] : rotA[j];
            x0 += x1;
            x1 = rotl32(x1, r);
            x1 ^= x0;
        }
        x0 += ks[(i + 1) % 3];
        x1 += ks[(i + 2) % 3] + (unsigned)(i + 1);
    }
    o0 = x0; o1 = x1;
}

__device__ inline float erfinv_f32(float x) {
    float w = -log1pf(-x * x);
    float p;
    if (w < 5.0f) {
        w -= 2.5f;
        p = 2.81022636e-08f;
        p = fmaf(p, w, 3.43273939e-07f);
        p = fmaf(p, w, -3.5233877e-06f);
        p = fmaf(p, w, -4.39150654e-06f);
        p = fmaf(p, w, 0.00021858087f);
        p = fmaf(p, w, -0.00125372503f);
        p = fmaf(p, w, -0.00417768164f);
        p = fmaf(p, w, 0.246640727f);
        p = fmaf(p, w, 1.50140941f);
    } else {
        w = sqrtf(w) - 3.0f;
        p = -0.000200214257f;
        p = fmaf(p, w, 0.000100950558f);
        p = fmaf(p, w, 0.00134934322f);
        p = fmaf(p, w, -0.00367342844f);
        p = fmaf(p, w, 0.00573950773f);
        p = fmaf(p, w, -0.0076224613f);
        p = fmaf(p, w, 0.00943887047f);
        p = fmaf(p, w, 1.00167406f);
        p = fmaf(p, w, 2.83297682f);
    }
    return p * x;
}

__device__ inline float jax_normal_4232(unsigned idx) {
    unsigned o0, o1;
    threefry2x32_042(0u, idx, o0, o1);
    unsigned bits = o0 ^ o1;
    unsigned fb = (bits >> 9) | 0x3f800000u;
    float f = __uint_as_float(fb) - 1.0f;              // [0, 1)
    const float lo = -0.99999994f;                     // nextafter(-1, 0)
    float u = f * (1.0f - lo) + lo;
    u = fmaxf(u, lo);
    return 1.41421356f * erfinv_f32(u);
}

// ---------------- int64/int32 index handling -------------------------------

__device__ inline int idx_at(const void* p, long long i, int is64) {
    return is64 ? (int)((const long long*)p)[i] : ((const int*)p)[i];
}

#define NBK 256
#define CAP 4864   // per-bucket edge capacity: mean 3906 + ~15 sigma

// detect dtype; also init bcnt=0 and gcur[t]=t*CAP (fixed bucket bases)
__global__ __launch_bounds__(256) void detect_idx64(const unsigned* __restrict__ raw,
                                                    int ne, int* flag,
                                                    int* __restrict__ bcnt,
                                                    int* __restrict__ gcur) {
    __shared__ int nz;
    if (threadIdx.x == 0) nz = 0;
    bcnt[threadIdx.x] = 0;
    gcur[threadIdx.x] = threadIdx.x * CAP;
    __syncthreads();
    int stride = ne / 2048;
    if (stride < 1) stride = 1;
    for (int k = threadIdx.x; k < 2048; k += 256) {
        long long j = (long long)k * stride;
        if (j < ne && raw[2 * j + 1] != 0u) nz = 1;
    }
    __syncthreads();
    if (threadIdx.x == 0) flag[0] = (nz == 0) ? 1 : 0;
}

// ---------------- single-pass bucketed edge partition ----------------------

#define CHUNK_MAX 4096

__global__ __launch_bounds__(256) void bucket_fill(const void* __restrict__ ei,
                                                   const int* __restrict__ flag,
                                                   int* __restrict__ gcur,
                                                   int* __restrict__ bcnt,
                                                   int2* __restrict__ pairs,
                                                   int ne, int npb, int chunk) {
    __shared__ int hist[NBK];
    __shared__ int basecur[NBK];
    __shared__ int sbuf[CHUNK_MAX];
    __shared__ int dbuf[CHUNK_MAX];
    int t = threadIdx.x;
    hist[t] = 0;
    __syncthreads();
    int is64 = flag[0];
    int c0 = blockIdx.x * chunk;
    int c1 = c0 + chunk; if (c1 > ne) c1 = ne;
    for (int i = c0 + t; i < c1; i += 256) {
        int s = idx_at(ei, i, is64);
        int d = idx_at(ei, (long long)ne + i, is64);
        sbuf[i - c0] = s;
        dbuf[i - c0] = d;
        atomicAdd(&hist[d / npb], 1);
    }
    __syncthreads();
    if (hist[t] > 0) {
        basecur[t] = atomicAdd(&gcur[t], hist[t]);
        atomicAdd(&bcnt[t], hist[t]);
    }
    __syncthreads();
    int nloc = c1 - c0;
    for (int li = t; li < nloc; li += 256) {
        int d = dbuf[li];
        int bb = d / npb;
        int slot = atomicAdd(&basecur[bb], 1);
        if (slot < (bb + 1) * CAP) pairs[slot] = make_int2(sbuf[li], d);
    }
}

// one block per bucket: LDS degree histogram -> wave scan -> rowptr/deg/dinv,
// LDS-cursor fill of csr_src; also zeroes sums (gtot floats, 256 blocks)
#define NPB_MAX 512
__global__ __launch_bounds__(256) void csr_build(const int2* __restrict__ pairs,
                                                 const int* __restrict__ bcnt,
                                                 int* __restrict__ rowptr,
                                                 int* __restrict__ degarr,
                                                 float* __restrict__ dinv,
                                                 int* __restrict__ csr_src,
                                                 float* __restrict__ sums, int gtot,
                                                 int n, int npb) {
    __shared__ int cnt[NPB_MAX];
    __shared__ int cur[NPB_MAX];
    int b = blockIdx.x;
    int t = threadIdx.x;
    int gi = b * 256 + t;
    if (gi < gtot) sums[gi] = 0.0f;
    int bstart = b * npb;
    int bn = n - bstart; if (bn > npb) bn = npb;
    if (bn <= 0) return;
    int e0 = b * CAP;
    int count = bcnt[b]; if (count > CAP) count = CAP;
    int e1 = e0 + count;

    for (int i = t; i < bn; i += 256) cnt[i] = 0;
    __syncthreads();
    for (int i = e0 + t; i < e1; i += 256)
        atomicAdd(&cnt[pairs[i].y - bstart], 1);
    __syncthreads();

    if (t < 64) {
        int running = 0;
        for (int base2 = 0; base2 < bn; base2 += 64) {
            int idx2 = base2 + t;
            int v = (idx2 < bn) ? cnt[idx2] : 0;
            int orig = v;
            #pragma unroll
            for (int off = 1; off < 64; off <<= 1) {
                int tmp = __shfl_up(v, off);
                if (t >= off) v += tmp;
            }
            if (idx2 < bn) cur[idx2] = e0 + running + (v - orig);
            running += __shfl(v, 63);
        }
    }
    __syncthreads();

    for (int ln = t; ln < bn; ln += 256) {
        rowptr[bstart + ln] = cur[ln];
        degarr[bstart + ln] = cnt[ln];
        dinv[bstart + ln] = rsqrtf((float)cnt[ln] + 1.0f);
    }
    __syncthreads();

    for (int i = e0 + t; i < e1; i += 256) {
        int2 p = pairs[i];
        int slot = atomicAdd(&cur[p.y - bstart], 1);
        csr_src[slot] = p.x;
    }
}

// ---------------- MFMA 64x64 linear layers ---------------------------------

__device__ inline void load_wfrags(const float* __restrict__ W,
                                   int cq, int cr, bf16x8 wf[2][4]) {
    #pragma unroll
    for (int ks = 0; ks < 2; ++ks)
        #pragma unroll
        for (int cb = 0; cb < 4; ++cb) {
            bf16x8 v;
            #pragma unroll
            for (int j = 0; j < 8; ++j) {
                int k = ks * 32 + cq * 8 + j;
                v[j] = (short)f2bf(W[k * 64 + cb * 16 + cr]);
            }
            wf[ks][cb] = v;
        }
}

__device__ inline void mfma_store(f32x4 acc[4], const float* __restrict__ dinv,
                                  unsigned short* __restrict__ Y,
                                  int rowbase, int cq, int cr, int nrows) {
    #pragma unroll
    for (int reg = 0; reg < 4; ++reg) {
        int r = rowbase + cq * 4 + reg;
        if (r < nrows) {
            float dv = dinv[r];
            #pragma unroll
            for (int cb = 0; cb < 4; ++cb)
                Y[(size_t)r * 64 + cb * 16 + cr] = f2bf(acc[cb][reg] * dv);
        }
    }
}

__global__ __launch_bounds__(256) void lin64_mfma_f32(const float* __restrict__ X,
                                                      const float* __restrict__ W,
                                                      const float* __restrict__ dinv,
                                                      unsigned short* __restrict__ Y,
                                                      int nrows) {
    int t = threadIdx.x;
    int lane = t & 63, wid = t >> 6;
    int cq = lane >> 4, cr = lane & 15;
    bf16x8 wf[2][4];
    load_wfrags(W, cq, cr, wf);
    int rowbase = (blockIdx.x * 4 + wid) * 16;
    if (rowbase >= nrows) return;
    int arow = rowbase + cr; if (arow >= nrows) arow = nrows - 1;
    const float* xr = X + (size_t)arow * 64;
    bf16x8 af[2];
    #pragma unroll
    for (int ks = 0; ks < 2; ++ks) {
        const float4* p = (const float4*)(xr + ks * 32 + cq * 8);
        float4 a = p[0], b = p[1];
        bf16x8 v;
        v[0] = (short)f2bf(a.x); v[1] = (short)f2bf(a.y);
        v[2] = (short)f2bf(a.z); v[3] = (short)f2bf(a.w);
        v[4] = (short)f2bf(b.x); v[5] = (short)f2bf(b.y);
        v[6] = (short)f2bf(b.z); v[7] = (short)f2bf(b.w);
        af[ks] = v;
    }
    f32x4 z = {0.0f, 0.0f, 0.0f, 0.0f};
    f32x4 acc[4] = {z, z, z, z};
    #pragma unroll
    for (int ks = 0; ks < 2; ++ks)
        #pragma unroll
        for (int cb = 0; cb < 4; ++cb)
            acc[cb] = __builtin_amdgcn_mfma_f32_16x16x32_bf16(af[ks], wf[ks][cb],
                                                              acc[cb], 0, 0, 0);
    mfma_store(acc, dinv, Y, rowbase, cq, cr, nrows);
}

__global__ __launch_bounds__(256) void lin64_mfma_bf16(const unsigned short* __restrict__ X,
                                                       const float* __restrict__ bin,
                                                       const float* __restrict__ W,
                                                       const float* __restrict__ dinv,
                                                       unsigned short* __restrict__ Y,
                                                       int nrows) {
    int t = threadIdx.x;
    int lane = t & 63, wid = t >> 6;
    int cq = lane >> 4, cr = lane & 15;
    bf16x8 wf[2][4];
    load_wfrags(W, cq, cr, wf);
    float bpre[2][8];
    #pragma unroll
    for (int ks = 0; ks < 2; ++ks)
        #pragma unroll
        for (int j = 0; j < 8; ++j)
            bpre[ks][j] = bin[ks * 32 + cq * 8 + j];
    int rowbase = (blockIdx.x * 4 + wid) * 16;
    if (rowbase >= nrows) return;
    int arow = rowbase + cr; if (arow >= nrows) arow = nrows - 1;
    const unsigned short* xr = X + (size_t)arow * 64;
    bf16x8 af[2];
    #pragma unroll
    for (int ks = 0; ks < 2; ++ks) {
        bf16x8 raw = *(const bf16x8*)(xr + ks * 32 + cq * 8);
        bf16x8 v;
        #pragma unroll
        for (int j = 0; j < 8; ++j) {
            float vv = bf2f((unsigned short)raw[j]) + bpre[ks][j];
            v[j] = (short)f2bf(fmaxf(vv, 0.0f));
        }
        af[ks] = v;
    }
    f32x4 z = {0.0f, 0.0f, 0.0f, 0.0f};
    f32x4 acc[4] = {z, z, z, z};
    #pragma unroll
    for (int ks = 0; ks < 2; ++ks)
        #pragma unroll
        for (int cb = 0; cb < 4; ++cb)
            acc[cb] = __builtin_amdgcn_mfma_f32_16x16x32_bf16(af[ks], wf[ks][cb],
                                                              acc[cb], 0, 0, 0);
    mfma_store(acc, dinv, Y, rowbase, cq, cr, nrows);
}

// ---------------- gather / pool / head -------------------------------------

__device__ inline float tree16(const float v[16]) {
    float s0 = (v[0] + v[1]) + (v[2] + v[3]);
    float s1 = (v[4] + v[5]) + (v[6] + v[7]);
    float s2 = (v[8] + v[9]) + (v[10] + v[11]);
    float s3 = (v[12] + v[13]) + (v[14] + v[15]);
    return (s0 + s1) + (s2 + s3);
}

// Full-wave column-parallel gather, masked batch-16 rounds (wave-uniform m).
// Out-of-range shfl lanes hold sl=0 (masked at load) -> read A row 0, zeroed
// by the uniform predicate; no clamp select needed.
__global__ __launch_bounds__(256) void gcn_gather(const unsigned short* __restrict__ A,
                                                  const float* __restrict__ dinv,
                                                  const int* __restrict__ rowptr,
                                                  const int* __restrict__ degarr,
                                                  const int* __restrict__ csr_src,
                                                  unsigned short* __restrict__ B, int n) {
    int t = threadIdx.x;
    int node = blockIdx.x * 4 + (t >> 6);    // wave-uniform
    int c = t & 63;
    if (node >= n) return;
    float acc = bf2f(A[(size_t)node * 64 + c]);           // self loop
    int beg = rowptr[node];
    int mt = degarr[node];
    for (int chunk = 0; chunk < mt; chunk += 64) {
        int m = mt - chunk; if (m > 64) m = 64;           // uniform
        int sl = (c < m) ? csr_src[beg + chunk + c] : 0;  // coalesced
        for (int j0 = 0; j0 < m; j0 += 16) {
            int mm = m - j0; if (mm > 16) mm = 16;        // uniform
            int sidx[16];
            #pragma unroll
            for (int j = 0; j < 16; ++j)
                sidx[j] = __shfl(sl, j0 + j);             // j0+j <= 63 always
            float v[16];
            #pragma unroll
            for (int j = 0; j < 16; ++j)
                v[j] = bf2f(A[(size_t)sidx[j] * 64 + c]);
            #pragma unroll
            for (int j = 0; j < 16; ++j)
                v[j] = (j < mm) ? v[j] : 0.0f;            // uniform predicate
            acc += tree16(v);
        }
    }
    B[(size_t)node * 64 + c] = f2bf(acc * dinv[node]);
}

#define POOL_NPW 32
__global__ __launch_bounds__(256) void pool_seg(const __hip_bfloat16* __restrict__ X,
                                                const float* __restrict__ b,
                                                const void* __restrict__ batch,
                                                const int* __restrict__ flag,
                                                float* __restrict__ sums,
                                                float* __restrict__ counts, int n) {
    int t = threadIdx.x;
    int c = t & 63;
    int wid = blockIdx.x * 4 + (t >> 6);
    int s0 = wid * POOL_NPW;
    if (s0 >= n) return;
    int s1 = s0 + POOL_NPW; if (s1 > n) s1 = n;
    int is64 = flag[0];
    float bc = b[c];
    float acc = 0.0f, cnt = 0.0f;
    int cur = idx_at(batch, s0, is64);
    int i = s0;
    for (; i + 2 <= s1; i += 2) {
        int g0 = idx_at(batch, i, is64);
        int g1 = idx_at(batch, i + 1, is64);
        float v0 = __bfloat162float(X[(size_t)i * 64 + c]);
        float v1 = __bfloat162float(X[(size_t)(i + 1) * 64 + c]);
        if (g0 != cur) {
            atomicAdd(&sums[(size_t)cur * 64 + c], acc);
            if (c == 0) atomicAdd(&counts[cur], cnt);
            acc = 0.0f; cnt = 0.0f; cur = g0;
        }
        acc += fmaxf(v0 + bc, 0.0f); cnt += 1.0f;
        if (g1 != cur) {
            atomicAdd(&sums[(size_t)cur * 64 + c], acc);
            if (c == 0) atomicAdd(&counts[cur], cnt);
            acc = 0.0f; cnt = 0.0f; cur = g1;
        }
        acc += fmaxf(v1 + bc, 0.0f); cnt += 1.0f;
    }
    if (i < s1) {
        int g0 = idx_at(batch, i, is64);
        float v0 = __bfloat162float(X[(size_t)i * 64 + c]);
        if (g0 != cur) {
            atomicAdd(&sums[(size_t)cur * 64 + c], acc);
            if (c == 0) atomicAdd(&counts[cur], cnt);
            acc = 0.0f; cnt = 0.0f; cur = g0;
        }
        acc += fmaxf(v0 + bc, 0.0f); cnt += 1.0f;
    }
    atomicAdd(&sums[(size_t)cur * 64 + c], acc);
    if (c == 0) atomicAdd(&counts[cur], cnt);
}

__global__ __launch_bounds__(64) void vae_head(const float* __restrict__ sums,
                                               const float* __restrict__ counts,
                                               const float* __restrict__ Wmu,
                                               const float* __restrict__ bmu,
                                               const float* __restrict__ Wlv,
                                               const float* __restrict__ blv,
                                               const float* __restrict__ Wd1,
                                               const float* __restrict__ bd1,
                                               const float* __restrict__ Wd2,
                                               const float* __restrict__ bd2,
                                               float* __restrict__ out) {
    int g = blockIdx.x;
    int t = threadIdx.x;  // 64 threads
    __shared__ float sp[64];
    __shared__ float sz[32];
    __shared__ float sh[64];

    float cnt = fmaxf(counts[g], 1.0f);
    sp[t] = sums[(size_t)g * 64 + t] / cnt;
    __syncthreads();

    if (t < 32) {
        float mu = bmu[t];
        float lv = blv[t];
        #pragma unroll
        for (int k = 0; k < 64; ++k) {
            float pk = sp[k];
            mu = fmaf(pk, Wmu[k * 32 + t], mu);
            lv = fmaf(pk, Wlv[k * 32 + t], lv);
        }
        unsigned idx = (unsigned)(g * 32 + t);
        float eps = jax_normal_4232(idx);
        float z = fmaf(eps, expf(0.5f * lv), mu);
        sz[t] = z;
        out[16384 + (size_t)g * 32 + t] = mu;       // mu block
        out[24576 + (size_t)g * 32 + t] = lv;       // logvar block
    }
    __syncthreads();

    float h = bd1[t];
    #pragma unroll
    for (int k = 0; k < 32; ++k) h = fmaf(sz[k], Wd1[k * 64 + t], h);
    h = fmaxf(h, 0.0f);
    sh[t] = h;
    __syncthreads();

    float r = bd2[t];
    #pragma unroll
    for (int k = 0; k < 64; ++k) r = fmaf(sh[k], Wd2[k * 64 + t], r);
    out[(size_t)g * 64 + t] = r;                    // recon block
}

// ---------------- launch ----------------------------------------------------

extern "C" void kernel_launch(void* const* d_in, const int* in_sizes, int n_in,
                              void* d_out, int out_size, void* d_ws, size_t ws_size,
                              hipStream_t stream) {
    const float* x    = (const float*)d_in[0];
    const void*  ei   = d_in[1];
    const void*  batch= d_in[2];
    const float* W1   = (const float*)d_in[3];
    const float* b1   = (const float*)d_in[4];
    const float* W2   = (const float*)d_in[5];
    const float* b2   = (const float*)d_in[6];
    const float* Wmu  = (const float*)d_in[7];
    const float* bmu  = (const float*)d_in[8];
    const float* Wlv  = (const float*)d_in[9];
    const float* blv  = (const float*)d_in[10];
    const float* Wd1  = (const float*)d_in[11];
    const float* bd1  = (const float*)d_in[12];
    const float* Wd2  = (const float*)d_in[13];
    const float* bd2  = (const float*)d_in[14];

    const int N = in_sizes[0] / 64;       // 100000
    const int E = in_sizes[1] / 2;        // 1000000
    const int G = 256;

    const int NPB = (N + NBK - 1) / NBK;          // 391 nodes per bucket
    const int nbu = (N + NPB - 1) / NPB;          // 256 buckets

    float* out = (float*)d_out;

    // workspace layout
    float* dinv = (float*)d_ws;                          // Npad floats
    __hip_bfloat16* A = (__hip_bfloat16*)(dinv + ((N + 255) & ~255)); // N*64 bf16
    __hip_bfloat16* B = A + (size_t)N * 64;              // N*64 bf16
    float* sums = (float*)(B + (size_t)N * 64);          // G*64
    float* cnts = sums + (size_t)G * 64;                 // G
    int*   flag = (int*)(cnts + G);                      // 1 (+pad to 256)
    int*   rowptr = flag + 256;                          // N (+pad)
    int*   degarr = rowptr + ((N + 255) & ~255);         // N (+pad)
    int*   bcnt = degarr + ((N + 255) & ~255);           // 256
    int*   gcur = bcnt + 256;                            // 256
    int*   csr_src = gcur + 256;                         // nbu*CAP
    int2*  pairs = (int2*)(csr_src + (((size_t)nbu * CAP + 1) & ~1ull)); // nbu*CAP

    const int blkRows  = (N + 3) / 4;
    const int blkLin   = (N + 63) / 64;                  // 16 rows/wave, 4 waves/blk
    const int blkPool  = (N + POOL_NPW * 4 - 1) / (POOL_NPW * 4);
    const int chunkE   = (E + NBK - 1) / NBK;            // edges per fill block (<=4096)
    const int gtot     = G * 64 + G;

    // index dtype detection + bcnt/gcur init
    detect_idx64<<<1, 256, 0, stream>>>((const unsigned*)ei, E, flag, bcnt, gcur);

    // single-pass bucketed partition + CSR build (csr_build also zeroes sums)
    bucket_fill<<<NBK, 256, 0, stream>>>(ei, flag, gcur, bcnt, pairs, E, NPB, chunkE);
    csr_build<<<nbu, 256, 0, stream>>>(pairs, bcnt, rowptr, degarr, dinv, csr_src,
                                       sums, gtot, N, NPB);

    // conv1: A = bf16(x@W1 * dinv) ; B = bf16(gather(A) * dinv)
    lin64_mfma_f32<<<blkLin, 256, 0, stream>>>(x, W1, dinv, (unsigned short*)A, N);
    gcn_gather<<<blkRows, 256, 0, stream>>>((const unsigned short*)A, dinv,
                                            rowptr, degarr, csr_src,
                                            (unsigned short*)B, N);

    // conv2: A = bf16(relu(B+b1)@W2 * dinv) ; B = bf16(gather(A) * dinv)
    lin64_mfma_bf16<<<blkLin, 256, 0, stream>>>((const unsigned short*)B, b1, W2,
                                                dinv, (unsigned short*)A, N);
    gcn_gather<<<blkRows, 256, 0, stream>>>((const unsigned short*)A, dinv,
                                            rowptr, degarr, csr_src,
                                            (unsigned short*)B, N);

    // pool (applies relu(B+b2)) + head
    pool_seg<<<blkPool, 256, 0, stream>>>(B, b2, batch, flag, sums, cnts, N);
    vae_head<<<G, 64, 0, stream>>>(sums, cnts, Wmu, bmu, Wlv, blv,
                                   Wd1, bd1, Wd2, bd2, out);
}